// Round 7
// baseline (1016.628 us; speedup 1.0000x reference)
//
#include <hip/hip_runtime.h>
#include <stdint.h>
#include <math.h>

// LightweightTransformerLayer for gfx950 — round 7: split pipeline, kA LDS
// pitch fix. B=8, C=256, N=64, P=256; 512 seqs x 256 tok x 256 ch.
//
// ROUND 7 FIX: kA staged x->bf16 at pitch 264B/channel (fp32-era value) while
// the region is sized for 132B -> writes overran into the A-frag and LN-stats
// regions; corrupted sum-of-squares made var negative -> rsqrtf -> NaN.
// Pitch is now 132B (= 64 tok * 2B + 4B pad), matching kD.
//
//  prep: weights -> bf16 FRAG-LINEAR (16x32 tile = 64 lanes x 16B).
//  kA: LN1 + QKV GEMM per 64-token block. Q,K written FRAG-LINEAR, V written
//      transposed row-major. Transposed-MFMA + xpose for Q/K.
//  kB: flash attention per (seq,head), 4 waves x 64 queries. K frags staged
//      linear (conflict-free b128), V^T swizzled. FULL-ROW softmax (256 keys)
//      -> 4 shfl per q-tile. P via per-wave LDS buffer. o overwrites own
//      consumed Q-frag block.
//  kC: proj GEMM + bias + residual -> x2 fp32 (d_out) + LN2 stats (global).
//  kD: LN2-apply + MLP1 GEMM + exact GELU -> m FRAG-LINEAR (xpose).
//  kE: MLP2 GEMM + bias + residual RMW d_out. A-frags direct from global.
//
// ws map (bytes): [0,1M) weights | [1M,2M) LN2 stats | [2M,69M) Qf (o
//   overlays) | [69M,136M) Kf | [136M,203M) V^T | m overlays Qf+Kf.

#define DEV static __device__ __forceinline__

typedef __bf16 bf16x8 __attribute__((ext_vector_type(8)));
typedef float  f32x4  __attribute__((ext_vector_type(4)));

union B8 { bf16x8 v; uint4 q; uint32_t u[4]; uint16_t h[8]; };

DEV uint16_t f2bf(float f) {
  uint32_t u = __float_as_uint(f);
  return (uint16_t)((u + 0x7FFFu + ((u >> 16) & 1u)) >> 16);  // RNE
}
DEV float bf2f(uint16_t h) { return __uint_as_float(((uint32_t)h) << 16); }
DEV uint32_t pk2(float a, float b) { return (uint32_t)f2bf(a) | ((uint32_t)f2bf(b) << 16); }

DEV f32x4 mfma16(const B8& a, const B8& b, f32x4 c) {
  return __builtin_amdgcn_mfma_f32_16x16x32_bf16(a.v, b.v, c, 0, 0, 0);
}
DEV uint32_t shfl_u(uint32_t v, int src) { return (uint32_t)__shfl((int)v, src, 64); }
DEV f32x4 vmax4(f32x4 a, f32x4 b) {
  f32x4 o;
  o[0] = fmaxf(a[0], b[0]); o[1] = fmaxf(a[1], b[1]);
  o[2] = fmaxf(a[2], b[2]); o[3] = fmaxf(a[3], b[3]);
  return o;
}
DEV f32x4 shfl4x(f32x4 v, int m) {
  f32x4 o;
#pragma unroll
  for (int i = 0; i < 4; ++i) o[i] = __shfl_xor(v[i], m, 64);
  return o;
}

// C-frag tiles (4 row-tiles, packed pk0=(r0,r1), pk1=(r2,r3)) -> A/B-frag of
// the TRANSPOSE. Verified end-to-end rounds 1-5.
// C/D: col=lane&15, row=(lane>>4)*4+i ; A/B: idx=lane&15, k-oct=(lane>>4)*8.
DEV void xpose(const uint32_t* pk0, const uint32_t* pk1, int kd, int g, int r, uint32_t* out) {
  const int sA = 32 * (g & 1) + r;
  const int sB = sA + 16;
  const int tA = 2 * kd, tB = 2 * kd + 1;
  uint32_t a0 = shfl_u(pk0[tA], sA), b0 = shfl_u(pk0[tB], sA);
  uint32_t a1 = shfl_u(pk1[tA], sA), b1 = shfl_u(pk1[tB], sA);
  uint32_t a2 = shfl_u(pk0[tA], sB), b2 = shfl_u(pk0[tB], sB);
  uint32_t a3 = shfl_u(pk1[tA], sB), b3 = shfl_u(pk1[tB], sB);
  const bool hi = g >= 2;
  out[0] = hi ? b0 : a0;
  out[1] = hi ? b1 : a1;
  out[2] = hi ? b2 : a2;
  out[3] = hi ? b3 : a3;
}

// ---------------------------------------------------------------------------
// prep: weights -> bf16 FRAG-LINEAR. Matrix [R][C]: tile (tr,tk) at
// (tr*(C/32)+tk)*512 + lane*8 + j, lane=(row&15)+16*((col>>3)&3), j=col&7.
// Segments (elems): wqkv_f @0 (196608, W_q rows scaled by SCALE*log2e),
// wproj_f @196608, w1_f @262144, w2_f @393216.
__global__ void transformer_prep(const float* __restrict__ wqkv,
                                 const float* __restrict__ wproj,
                                 const float* __restrict__ w1,
                                 const float* __restrict__ w2,
                                 uint16_t* __restrict__ dst) {
  int e = blockIdx.x * 256 + threadIdx.x;  // 2048*256 = 524288 exactly
  const float* src; int C, local;
  if (e < 196608)      { src = wqkv;  C = 256; local = e; }
  else if (e < 262144) { src = wproj; C = 256; local = e - 196608; }
  else if (e < 393216) { src = w1;    C = 256; local = e - 262144; }
  else                 { src = w2;    C = 512; local = e - 393216; }
  int k32 = C >> 5;
  int tile = local >> 9, within = local & 511;
  int ln = within >> 3, j = within & 7;
  int tr = tile / k32, tk = tile - tr * k32;
  int row = tr * 16 + (ln & 15), col = tk * 32 + (ln >> 4) * 8 + j;
  float v = src[row * C + col];
  if (e < 65536) v *= 0.18033688011112042f;  // SCALE * log2(e) into W_q
  dst[e] = f2bf(v);
}

// ---------------------------------------------------------------------------
// kA: LN1 + QKV. WG = (seq, 64-token quarter), 256 thr / 4 waves.
// LDS: x_bf [256 c][132B pitch] @0 (33792) | A-frags 32KB @33792 |
//      stat partials [16cq][16pg]x32B @66560 (8192) | ln1 g/b @74752 (2KB).
__global__ __launch_bounds__(256, 2) void transformer_kA(
    const float* __restrict__ x,
    const float* __restrict__ ln1g, const float* __restrict__ ln1b,
    const uint16_t* __restrict__ wqkvf,
    uint16_t* __restrict__ qf, uint16_t* __restrict__ kf,
    uint16_t* __restrict__ vt) {
  __shared__ __attribute__((aligned(16))) uint8_t lds[76800];
  const int tid = threadIdx.x;
  const int lane = tid & 63;
  const int wv = tid >> 6;
  const int r = lane & 15, g = lane >> 4;
  const int bid = blockIdx.x;
  const int s = bid >> 2, q64 = bid & 3;
  const int tok0 = q64 * 64;
  const float* xs = x + (size_t)(s >> 6) * 4194304 + (size_t)(s & 63) * 256 + tok0;
  const f32x4 fz = {0.f, 0.f, 0.f, 0.f};

  ((float*)(lds + 74752))[tid] = ln1g[tid];
  ((float*)(lds + 75776))[tid] = ln1b[tid];

  // ---- phase 1: read x (f32x4, coalesced), partial LN sums, x->bf16 LDS ----
  {
    const int pg = tid & 15, cq = tid >> 4;
    const int p4 = pg * 4;
    f32x4 s1 = fz, s2 = fz;
#pragma unroll
    for (int j = 0; j < 16; ++j) {
      int c = j * 16 + cq;
      f32x4 v = *(const f32x4*)(xs + (size_t)c * 16384 + p4);
      s1 += v; s2 += v * v;
      uint2 w; w.x = pk2(v[0], v[1]); w.y = pk2(v[2], v[3]);
      *(uint2*)(lds + c * 132 + p4 * 2) = w;   // pitch 132B = 64 tok + pad
    }
    *(f32x4*)(lds + 66560 + (cq * 16 + pg) * 32) = s1;
    *(f32x4*)(lds + 66560 + (cq * 16 + pg) * 32 + 16) = s2;
  }
  __syncthreads();

  // ---- phase 1b: per-token stats + normalize + pack A-frags ----------------
  {
    const int tokl = 16 * wv + r;            // this thread's token row
    const int pg = tokl >> 2, e = tokl & 3;
    float su = 0.f, sq = 0.f;
#pragma unroll
    for (int cq = 0; cq < 16; ++cq) {
      su += *(const float*)(lds + 66560 + (cq * 16 + pg) * 32 + e * 4);
      sq += *(const float*)(lds + 66560 + (cq * 16 + pg) * 32 + 16 + e * 4);
    }
    float mu = su * (1.0f / 256.0f);
    float var = sq * (1.0f / 256.0f) - mu * mu;
    float rs = rsqrtf(var + 1e-5f);
#pragma unroll
    for (int tk = 0; tk < 8; ++tk) {
      int c0 = 32 * tk + 8 * g;
      uint32_t pk[4];
#pragma unroll
      for (int q = 0; q < 4; ++q) {
        float lo, hi;
        {
          int c = c0 + 2 * q;
          uint16_t raw = *(const uint16_t*)(lds + c * 132 + tokl * 2);
          float gg = ((const float*)(lds + 74752))[c];
          float bb = ((const float*)(lds + 75776))[c];
          lo = (bf2f(raw) - mu) * rs * gg + bb;
        }
        {
          int c = c0 + 2 * q + 1;
          uint16_t raw = *(const uint16_t*)(lds + c * 132 + tokl * 2);
          float gg = ((const float*)(lds + 74752))[c];
          float bb = ((const float*)(lds + 75776))[c];
          hi = (bf2f(raw) - mu) * rs * gg + bb;
        }
        pk[q] = pk2(lo, hi);
      }
      uint4 t; t.x = pk[0]; t.y = pk[1]; t.z = pk[2]; t.w = pk[3];
      *(uint4*)(lds + 33792 + (wv * 8 + tk) * 1024 + lane * 16) = t;
    }
  }
  __syncthreads();

  // ---- phase 2: GEMM. 3 passes/wave, each 64 cols = one (m,hd) slice -------
#pragma unroll 1
  for (int pp = 0; pp < 3; ++pp) {
    const int n0 = wv * 192 + pp * 64;
    const int mi = n0 >> 8, hd = (n0 >> 6) & 3;
    const int s4hd = s * 4 + hd;
    f32x4 acc[4][4];
#pragma unroll
    for (int a = 0; a < 4; ++a)
#pragma unroll
      for (int b = 0; b < 4; ++b) acc[a][b] = fz;

    if (mi < 2) {
      // TRANSPOSED compute: acc[nt][tt] rows=n, cols=tok -> xpose -> frags
#pragma unroll
      for (int kt = 0; kt < 8; ++kt) {
        B8 hf[4];
#pragma unroll
        for (int tt = 0; tt < 4; ++tt)
          hf[tt].q = *(const uint4*)(lds + 33792 + (tt * 8 + kt) * 1024 + lane * 16);
#pragma unroll
        for (int nt = 0; nt < 4; ++nt) {
          B8 wf_;
          wf_.q = *(const uint4*)(wqkvf + (size_t)((((n0 >> 4) + nt) * 8 + kt) * 512) + lane * 8);
#pragma unroll
          for (int tt = 0; tt < 4; ++tt) acc[nt][tt] = mfma16(wf_, hf[tt], acc[nt][tt]);
        }
      }
      uint16_t* dstb = (mi == 0) ? qf : kf;
#pragma unroll
      for (int tt = 0; tt < 4; ++tt) {
        uint32_t p0[4], p1[4];
#pragma unroll
        for (int nt = 0; nt < 4; ++nt) {
          p0[nt] = pk2(acc[nt][tt][0], acc[nt][tt][1]);
          p1[nt] = pk2(acc[nt][tt][2], acc[nt][tt][3]);
        }
        int qtg = q64 * 4 + tt;
#pragma unroll
        for (int kd = 0; kd < 2; ++kd) {
          uint32_t ofr[4];
          xpose(p0, p1, kd, g, r, ofr);
          uint4 t; t.x = ofr[0]; t.y = ofr[1]; t.z = ofr[2]; t.w = ofr[3];
          *(uint4*)(dstb + (size_t)(((s4hd * 16 + qtg) * 2 + kd) * 512) + lane * 8) = t;
        }
      }
    } else {
      // NORMAL compute: rows=tok, cols=d -> V^T scatter (uint2 per lane)
#pragma unroll
      for (int kt = 0; kt < 8; ++kt) {
        B8 hf[4];
#pragma unroll
        for (int rt = 0; rt < 4; ++rt)
          hf[rt].q = *(const uint4*)(lds + 33792 + (rt * 8 + kt) * 1024 + lane * 16);
#pragma unroll
        for (int ct = 0; ct < 4; ++ct) {
          B8 wf_;
          wf_.q = *(const uint4*)(wqkvf + (size_t)((((n0 >> 4) + ct) * 8 + kt) * 512) + lane * 8);
#pragma unroll
          for (int rt = 0; rt < 4; ++rt) acc[rt][ct] = mfma16(hf[rt], wf_, acc[rt][ct]);
        }
      }
#pragma unroll
      for (int rt = 0; rt < 4; ++rt) {
#pragma unroll
        for (int ct = 0; ct < 4; ++ct) {
          int d = 16 * ct + r;
          int tokr = tok0 + 16 * rt + 4 * g;
          uint2 pv;
          pv.x = pk2(acc[rt][ct][0], acc[rt][ct][1]);
          pv.y = pk2(acc[rt][ct][2], acc[rt][ct][3]);
          *(uint2*)(vt + (size_t)(s4hd * 64 + d) * 256 + tokr) = pv;
        }
      }
    }
  }
}

// ---------------------------------------------------------------------------
// kB: flash attention per (seq, head). 256 thr / 4 waves, wave owns 64 q.
// LDS: K frag-linear 32KB @0 (conflict-free b128) | V^T swizzled 32KB @32768 |
//      P per-wave 4KB @65536+wv*4096. Full-row softmax; o overwrites own
//      Q-frag block after Q consumed (same-wave, no barrier needed).
__global__ __launch_bounds__(256, 2) void transformer_kB(
    uint16_t* __restrict__ qf, const uint16_t* __restrict__ kf,
    const uint16_t* __restrict__ vt) {
  __shared__ __attribute__((aligned(16))) uint8_t lds[81920];
  const int tid = threadIdx.x;
  const int lane = tid & 63;
  const int wv = tid >> 6;
  const int r = lane & 15, g = lane >> 4;
  const int bid = blockIdx.x;
  const int s4hd = bid;                   // bid = s*4 + hd
  const f32x4 fz = {0.f, 0.f, 0.f, 0.f};

  // stage K (frag-linear, straight copy) and V^T (swizzled)
#pragma unroll
  for (int i = 0; i < 8; ++i) {
    int off = i * 256 + tid;
    *(uint4*)(lds + off * 16) = *(const uint4*)(kf + (size_t)s4hd * 16384 + off * 8);
  }
#pragma unroll
  for (int i = 0; i < 8; ++i) {
    int f = i * 256 + tid;
    int d = f >> 5, t8 = (f & 31) * 8;
    uint4 v = *(const uint4*)(vt + (size_t)s4hd * 16384 + d * 256 + t8);
    *(uint4*)(lds + 32768 + ((d * 512 + t8 * 2) ^ ((d & 7) << 4))) = v;
  }
  __syncthreads();

  uint8_t* Plds = lds + 65536 + wv * 4096;   // [16 q][128 keys] bf16, swizzled

#pragma unroll 1
  for (int qt4 = 0; qt4 < 4; ++qt4) {
    const int qtg = wv * 4 + qt4;
    B8 qb[2];
#pragma unroll
    for (int kd = 0; kd < 2; ++kd)
      qb[kd].q = *(const uint4*)(qf + (size_t)(((s4hd * 16 + qtg) * 2 + kd) * 512) + lane * 8);

    // S^T full row: sT[kt] covers keys 16kt+4g..+3 (col = query = r)
    f32x4 sT[16];
#pragma unroll
    for (int kt = 0; kt < 16; ++kt) sT[kt] = fz;
#pragma unroll
    for (int kt = 0; kt < 16; ++kt) {
#pragma unroll
      for (int kd = 0; kd < 2; ++kd) {
        B8 ka;
        ka.q = *(const uint4*)(lds + (kt * 2 + kd) * 1024 + lane * 16);
        sT[kt] = mfma16(ka, qb[kd], sT[kt]);
      }
    }
    // full-row softmax (log2 domain): tree max + 2 shfl (across g only)
    f32x4 t8v[8];
#pragma unroll
    for (int i = 0; i < 8; ++i) t8v[i] = vmax4(sT[i], sT[i + 8]);
#pragma unroll
    for (int i = 0; i < 4; ++i) t8v[i] = vmax4(t8v[i], t8v[i + 4]);
    f32x4 tm = vmax4(vmax4(t8v[0], t8v[1]), vmax4(t8v[2], t8v[3]));
    float mx = fmaxf(fmaxf(tm[0], tm[1]), fmaxf(tm[2], tm[3]));
    mx = fmaxf(mx, __shfl_xor(mx, 16, 64));
    mx = fmaxf(mx, __shfl_xor(mx, 32, 64));
    f32x4 ss = fz;
#pragma unroll
    for (int kt = 0; kt < 16; ++kt) {
#pragma unroll
      for (int i = 0; i < 4; ++i) sT[kt][i] = exp2f(sT[kt][i] - mx);
      ss += sT[kt];
    }
    float l = ss[0] + ss[1] + ss[2] + ss[3];
    l += __shfl_xor(l, 16, 64);
    l += __shfl_xor(l, 32, 64);
    float inv = 1.0f / l;

    // PV in two key-halves through per-wave P buffer
    f32x4 oT[4];
#pragma unroll
    for (int dt = 0; dt < 4; ++dt) oT[dt] = fz;
#pragma unroll
    for (int kh = 0; kh < 2; ++kh) {
#pragma unroll
      for (int kt8 = 0; kt8 < 8; ++kt8) {
        int kt = kh * 8 + kt8;
        uint2 pv;
        pv.x = pk2(sT[kt][0], sT[kt][1]);
        pv.y = pk2(sT[kt][2], sT[kt][3]);
        *(uint2*)(Plds + ((r * 256 + kt8 * 32 + 8 * g) ^ ((r & 7) << 4))) = pv;
      }
#pragma unroll
      for (int ks = 0; ks < 4; ++ks) {
        B8 pb;
        pb.q = *(const uint4*)(Plds + ((r * 256 + ks * 64 + 16 * g) ^ ((r & 7) << 4)));
#pragma unroll
        for (int dt = 0; dt < 4; ++dt) {
          int d = 16 * dt + r;
          B8 va;
          va.q = *(const uint4*)(lds + 32768 + ((d * 512 + (128 * kh + 32 * ks + 8 * g) * 2) ^ ((d & 7) << 4)));
          oT[dt] = mfma16(va, pb, oT[dt]);   // O^T: rows=d, col=q=r
        }
      }
    }
    // o -> this q-tile's own (already consumed) Q-frag block: [tok][64 d]
#pragma unroll
    for (int dt = 0; dt < 4; ++dt) {
      uint2 ov;
      ov.x = pk2(oT[dt][0] * inv, oT[dt][1] * inv);
      ov.y = pk2(oT[dt][2] * inv, oT[dt][3] * inv);
      *(uint2*)(qf + (size_t)s4hd * 16384 + (16 * qtg + r) * 64 + 16 * dt + 4 * g) = ov;
    }
  }
}

// ---------------------------------------------------------------------------
// kC: proj + bias + residual -> x2 fp32 (d_out) + LN2 stats -> global.
// WG = 64-token block, 256 thr. LDS: o A-frags 32KB @0 | partials @32768 (2KB).
__global__ __launch_bounds__(256, 2) void transformer_kC(
    const float* __restrict__ x, const float* __restrict__ bproj,
    const uint16_t* __restrict__ wprojf,
    const uint16_t* __restrict__ o,      // = qf region, [s4hd][tok][64]
    float2* __restrict__ stats,
    float* __restrict__ out) {
  __shared__ __attribute__((aligned(16))) uint8_t lds[34816];
  const int tid = threadIdx.x;
  const int lane = tid & 63;
  const int wv = tid >> 6;
  const int r = lane & 15, g = lane >> 4;
  const int bid = blockIdx.x;
  const int s = bid >> 2, q64 = bid & 3;
  const int tok0 = q64 * 64;
  const float* xs = x + (size_t)(s >> 6) * 4194304 + (size_t)(s & 63) * 256;
  float* outp = out + (size_t)(s >> 6) * 4194304 + (size_t)(s & 63) * 256;
  const f32x4 fz = {0.f, 0.f, 0.f, 0.f};

  // stage o as A-frags (thread's chunk IS its frag data)
#pragma unroll
  for (int tk = 0; tk < 8; ++tk) {
    int c0 = 32 * tk + 8 * g;
    int hd = c0 >> 6, d0 = c0 & 63;
    int tok = tok0 + 16 * wv + r;
    uint4 v = *(const uint4*)(o + (size_t)(s * 4 + hd) * 16384 + tok * 64 + d0);
    *(uint4*)(lds + (wv * 8 + tk) * 1024 + lane * 16) = v;
  }
  __syncthreads();

  const int n0 = wv * 64;
  f32x4 acc[4][4];
#pragma unroll
  for (int a = 0; a < 4; ++a)
#pragma unroll
    for (int b = 0; b < 4; ++b) acc[a][b] = fz;
#pragma unroll
  for (int kt = 0; kt < 8; ++kt) {
    B8 of[4];
#pragma unroll
    for (int rt = 0; rt < 4; ++rt)
      of[rt].q = *(const uint4*)(lds + (rt * 8 + kt) * 1024 + lane * 16);
#pragma unroll
    for (int ct = 0; ct < 4; ++ct) {
      B8 wf_;
      wf_.q = *(const uint4*)(wprojf + (size_t)((((n0 >> 4) + ct) * 8 + kt) * 512) + lane * 8);
#pragma unroll
      for (int rt = 0; rt < 4; ++rt) acc[rt][ct] = mfma16(of[rt], wf_, acc[rt][ct]);
    }
  }
  // epilogue: x2 = acc + bias + x ; accumulate LN2 partials
  f32x4 s1a[4], s2a[4];
#pragma unroll
  for (int rt = 0; rt < 4; ++rt) { s1a[rt] = fz; s2a[rt] = fz; }
#pragma unroll
  for (int ct = 0; ct < 4; ++ct) {
    int c = n0 + 16 * ct + r;
    float bias = bproj[c];
#pragma unroll
    for (int rt = 0; rt < 4; ++rt) {
      int p = tok0 + 16 * rt + 4 * g;
      f32x4 res = *(const f32x4*)(xs + (size_t)c * 16384 + p);
      f32x4 x2v;
#pragma unroll
      for (int i = 0; i < 4; ++i) x2v[i] = acc[rt][ct][i] + bias + res[i];
      *(f32x4*)(outp + (size_t)c * 16384 + p) = x2v;
      s1a[rt] += x2v;
      s2a[rt] += x2v * x2v;
    }
  }
#pragma unroll
  for (int rt = 0; rt < 4; ++rt) {
#pragma unroll
    for (int m = 1; m < 16; m <<= 1) {
      s1a[rt] += shfl4x(s1a[rt], m);
      s2a[rt] += shfl4x(s2a[rt], m);
    }
  }
  if (r == 0) {
#pragma unroll
    for (int rt = 0; rt < 4; ++rt)
#pragma unroll
      for (int i = 0; i < 4; ++i) {
        float2 pr; pr.x = s1a[rt][i]; pr.y = s2a[rt][i];
        *(float2*)(lds + 32768 + ((16 * rt + 4 * g + i) * 4 + wv) * 8) = pr;
      }
  }
  __syncthreads();
  if (tid < 64) {
    float su = 0.f, sq = 0.f;
#pragma unroll
    for (int w2 = 0; w2 < 4; ++w2) {
      float2 pr = *(const float2*)(lds + 32768 + (tid * 4 + w2) * 8);
      su += pr.x; sq += pr.y;
    }
    float mu = su * (1.0f / 256.0f);
    float var = sq * (1.0f / 256.0f) - mu * mu;
    float2 st; st.x = mu; st.y = rsqrtf(var + 1e-5f);
    stats[bid * 64 + tid] = st;
  }
}

// ---------------------------------------------------------------------------
// kD: LN2-apply + MLP1 + exact GELU -> m FRAG-LINEAR. WG = 64-token block.
// LDS: x2bf [256 c][132B pitch] @0 (33792) | A-frags 32KB @33792.
__global__ __launch_bounds__(256, 2) void transformer_kD(
    const float* __restrict__ ln2g, const float* __restrict__ ln2b,
    const uint16_t* __restrict__ w1f, const float* __restrict__ bm1,
    const float2* __restrict__ stats,
    const float* __restrict__ out,
    uint16_t* __restrict__ mf) {
  __shared__ __attribute__((aligned(16))) uint8_t lds[66560];
  const int tid = threadIdx.x;
  const int lane = tid & 63;
  const int wv = tid >> 6;
  const int r = lane & 15, g = lane >> 4;
  const int bid = blockIdx.x;
  const int s = bid >> 2, q64 = bid & 3;
  const int tok0 = q64 * 64;
  const float* outp = out + (size_t)(s >> 6) * 4194304 + (size_t)(s & 63) * 256;
  const f32x4 fz = {0.f, 0.f, 0.f, 0.f};

  // phase 1: read x2 (f32x4), LN2-apply, bf16 -> LDS [c][132B]
  {
    const int pg = tid & 15, cq = tid >> 4;
    const int p4 = pg * 4;
    float2 st[4];
#pragma unroll
    for (int e = 0; e < 4; ++e) st[e] = stats[bid * 64 + p4 + e];
#pragma unroll
    for (int j = 0; j < 16; ++j) {
      int c = j * 16 + cq;
      f32x4 v = *(const f32x4*)(outp + (size_t)c * 16384 + tok0 + p4);
      float gg = ln2g[c];
      float bb = ln2b[c];
      float n0v = (v[0] - st[0].x) * st[0].y * gg + bb;
      float n1v = (v[1] - st[1].x) * st[1].y * gg + bb;
      float n2v = (v[2] - st[2].x) * st[2].y * gg + bb;
      float n3v = (v[3] - st[3].x) * st[3].y * gg + bb;
      uint2 w; w.x = pk2(n0v, n1v); w.y = pk2(n2v, n3v);
      *(uint2*)(lds + c * 132 + p4 * 2) = w;
    }
  }
  __syncthreads();
  // phase 1b: pack A-frags (already normalized)
  {
    const int tokl = 16 * wv + r;
#pragma unroll
    for (int tk = 0; tk < 8; ++tk) {
      int c0 = 32 * tk + 8 * g;
      uint32_t pk[4];
#pragma unroll
      for (int q = 0; q < 4; ++q) {
        uint16_t a = *(const uint16_t*)(lds + (c0 + 2 * q) * 132 + tokl * 2);
        uint16_t b = *(const uint16_t*)(lds + (c0 + 2 * q + 1) * 132 + tokl * 2);
        pk[q] = (uint32_t)a | ((uint32_t)b << 16);
      }
      uint4 t; t.x = pk[0]; t.y = pk[1]; t.z = pk[2]; t.w = pk[3];
      *(uint4*)(lds + 33792 + (wv * 8 + tk) * 1024 + lane * 16) = t;
    }
  }
  __syncthreads();

  // GEMM (transposed): 2 passes x 64 hidden cols; GELU; xpose -> m frag-linear
#pragma unroll 1
  for (int pp = 0; pp < 2; ++pp) {
    const int n0 = wv * 128 + pp * 64;
    f32x4 acc[4][4];
#pragma unroll
    for (int a = 0; a < 4; ++a)
#pragma unroll
      for (int b = 0; b < 4; ++b) acc[a][b] = fz;
#pragma unroll
    for (int kt = 0; kt < 8; ++kt) {
      B8 hf[4];
#pragma unroll
      for (int tt = 0; tt < 4; ++tt)
        hf[tt].q = *(const uint4*)(lds + 33792 + (tt * 8 + kt) * 1024 + lane * 16);
#pragma unroll
      for (int nt = 0; nt < 4; ++nt) {
        B8 wf_;
        wf_.q = *(const uint4*)(w1f + (size_t)((((n0 >> 4) + nt) * 8 + kt) * 512) + lane * 8);
#pragma unroll
        for (int tt = 0; tt < 4; ++tt) acc[nt][tt] = mfma16(wf_, hf[tt], acc[nt][tt]);
      }
    }
    // bias + exact GELU (rows = n = 16nt + 4g + i)
#pragma unroll
    for (int nt = 0; nt < 4; ++nt) {
      f32x4 b4 = *(const f32x4*)(bm1 + n0 + 16 * nt + 4 * g);
#pragma unroll
      for (int tt = 0; tt < 4; ++tt) {
#pragma unroll
        for (int i = 0; i < 4; ++i) {
          float vv = acc[nt][tt][i] + b4[i];
          acc[nt][tt][i] = 0.5f * vv * (1.0f + erff(vv * 0.70710678118654752440f));
        }
      }
    }
#pragma unroll
    for (int tt = 0; tt < 4; ++tt) {
      uint32_t p0[4], p1[4];
#pragma unroll
      for (int nt = 0; nt < 4; ++nt) {
        p0[nt] = pk2(acc[nt][tt][0], acc[nt][tt][1]);
        p1[nt] = pk2(acc[nt][tt][2], acc[nt][tt][3]);
      }
#pragma unroll
      for (int kd = 0; kd < 2; ++kd) {
        uint32_t ofr[4];
        xpose(p0, p1, kd, g, r, ofr);
        uint4 t; t.x = ofr[0]; t.y = ofr[1]; t.z = ofr[2]; t.w = ofr[3];
        *(uint4*)(mf + (size_t)(((bid * 4 + tt) * 16 + (n0 >> 5) + kd) * 512) + lane * 8) = t;
      }
    }
  }
}

// ---------------------------------------------------------------------------
// kE: MLP2 + bias + residual RMW. WG = 64-token block, A-frags from global.
__global__ __launch_bounds__(256, 2) void transformer_kE(
    const uint16_t* __restrict__ w2f, const float* __restrict__ bm2,
    const uint16_t* __restrict__ mf,
    float* __restrict__ out) {
  const int tid = threadIdx.x;
  const int lane = tid & 63;
  const int wv = tid >> 6;
  const int r = lane & 15, g = lane >> 4;
  const int bid = blockIdx.x;
  const int s = bid >> 2, q64 = bid & 3;
  const int tok0 = q64 * 64;
  float* outp = out + (size_t)(s >> 6) * 4194304 + (size_t)(s & 63) * 256;
  const f32x4 fz = {0.f, 0.f, 0.f, 0.f};

  f32x4 acc[4][4];
#pragma unroll
  for (int a = 0; a < 4; ++a)
#pragma unroll
    for (int b = 0; b < 4; ++b) acc[a][b] = fz;
#pragma unroll
  for (int kt = 0; kt < 16; ++kt) {
    B8 a[4];
#pragma unroll
    for (int rt = 0; rt < 4; ++rt)
      a[rt].q = *(const uint4*)(mf + (size_t)(((bid * 4 + rt) * 16 + kt) * 512) + lane * 8);
#pragma unroll
    for (int ct = 0; ct < 4; ++ct) {
      B8 wf_;
      wf_.q = *(const uint4*)(w2f + (size_t)(((wv * 4 + ct) * 16 + kt) * 512) + lane * 8);
#pragma unroll
      for (int rt = 0; rt < 4; ++rt) acc[rt][ct] = mfma16(a[rt], wf_, acc[rt][ct]);
    }
  }
#pragma unroll
  for (int ct = 0; ct < 4; ++ct) {
    int c = wv * 64 + 16 * ct + r;
    float bias = bm2[c];
#pragma unroll
    for (int rt = 0; rt < 4; ++rt) {
      int p = tok0 + 16 * rt + 4 * g;
      f32x4 res = *(const f32x4*)(outp + (size_t)c * 16384 + p);
      f32x4 o;
#pragma unroll
      for (int i = 0; i < 4; ++i) o[i] = res[i] + acc[rt][ct][i] + bias;
      *(f32x4*)(outp + (size_t)c * 16384 + p) = o;
    }
  }
}

// ---------------------------------------------------------------------------
extern "C" void kernel_launch(void* const* d_in, const int* in_sizes, int n_in,
                              void* d_out, int out_size, void* d_ws, size_t ws_size,
                              hipStream_t stream) {
  (void)in_sizes; (void)n_in; (void)out_size; (void)ws_size;
  const float* x     = (const float*)d_in[0];
  const float* wqkv  = (const float*)d_in[1];
  const float* wproj = (const float*)d_in[2];
  const float* bproj = (const float*)d_in[3];
  const float* ln1g  = (const float*)d_in[4];
  const float* ln1b  = (const float*)d_in[5];
  const float* ln2g  = (const float*)d_in[6];
  const float* ln2b  = (const float*)d_in[7];
  const float* w1    = (const float*)d_in[8];
  const float* bm1   = (const float*)d_in[9];
  const float* w2    = (const float*)d_in[10];
  const float* bm2   = (const float*)d_in[11];
  float* out = (float*)d_out;

  uint16_t* ws16 = (uint16_t*)d_ws;
  uint16_t* wbf  = ws16;                                // 524288 elems (1MB)
  float2*  stats = (float2*)((char*)d_ws + 1048576);    // 131072 float2 (1MB)
  uint16_t* qfrag = ws16 + 1048576;                     // 33554432 elems (67MB)
  uint16_t* kfrag = qfrag + 33554432;                   // 67MB
  uint16_t* vtb   = kfrag + 33554432;                   // 67MB
  uint16_t* mfrag = qfrag;                              // overlays Q+K (134MB)

  transformer_prep<<<2048, 256, 0, stream>>>(wqkv, wproj, w1, w2, wbf);
  transformer_kA<<<2048, 256, 0, stream>>>(x, ln1g, ln1b, wbf, qfrag, kfrag, vtb);
  transformer_kB<<<2048, 256, 0, stream>>>(qfrag, kfrag, vtb);
  transformer_kC<<<2048, 256, 0, stream>>>(x, bproj, wbf + 196608, qfrag, stats, out);
  transformer_kD<<<2048, 256, 0, stream>>>(ln2g, ln2b, wbf + 262144, bm1, stats, out, mfrag);
  transformer_kE<<<2048, 256, 0, stream>>>(wbf + 393216, bm2, mfrag, out);
}